// Round 1
// baseline (208.049 us; speedup 1.0000x reference)
//
#include <hip/hip_runtime.h>

// MMD loss: source (4096,256) fp32, target (4096,256) fp32 -> scalar fp32.
// total = concat -> n=8192 rows, D=256.
// bandwidth via closed form: sum(l2) = 2n*S - 2*||m||^2 (relu effects negligible).
// Main pass: G = T*T^T via bf16 MFMA (16x16x32), epilogue computes
// K = t + t^2 + t^4 + t^8 + t^16 with t = exp2(-l2 * log2(e)/(16*bw)),
// signed-summed with s_i*s_j; upper-triangle tiles only (x2 off-diagonal).

#define NROWS 8192
#define BHALF 4096
#define DDIM  256
#define TILE  128
// LDS row stride: 64 bf16 + 8 pad = 72 shorts = 144 B (16B-aligned, 4-bank stagger)
#define LDSTR 72

typedef __attribute__((ext_vector_type(8))) short bf16x8;
typedef __attribute__((ext_vector_type(4))) float f32x4;

struct Ws {
  double signed_sum;        // 0
  float  coef;              // 8
  float  pad0;              // 12
  float  Spart[64];         // 16
  float  mpart[64][256];    // per-block partial column sums
  float  sq[NROWS];         // fp32 row norms
};

__device__ __forceinline__ unsigned short f2bf(float x) {
  unsigned int u = __builtin_bit_cast(unsigned int, x);
  return (unsigned short)((u + 0x7fffu + ((u >> 16) & 1u)) >> 16);
}

__device__ __forceinline__ const float* row_ptr(const float* src, const float* tgt, int i) {
  return (i < BHALF) ? (src + (size_t)i * DDIM) : (tgt + (size_t)(i - BHALF) * DDIM);
}

__global__ void k_init(Ws* ws) {
  if (threadIdx.x == 0) ws->signed_sum = 0.0;
}

// 64 blocks x 256 threads: per-wave 32 rows. Produces sq[], per-block Spart, mpart.
__global__ __launch_bounds__(256) void k_rowstats(const float* __restrict__ src,
                                                  const float* __restrict__ tgt,
                                                  Ws* __restrict__ ws) {
  __shared__ float cls[4][256];
  __shared__ float swave[4];
  int tid = threadIdx.x, wave = tid >> 6, lane = tid & 63;
  int wave_g = blockIdx.x * 4 + wave;          // 0..255, 32 rows each
  float c0 = 0.f, c1 = 0.f, c2 = 0.f, c3 = 0.f, Sw = 0.f;
  for (int r = 0; r < 32; ++r) {
    int row = wave_g * 32 + r;
    const float4* rp = (const float4*)row_ptr(src, tgt, row);
    float4 v = rp[lane];
    c0 += v.x; c1 += v.y; c2 += v.z; c3 += v.w;
    float s = v.x * v.x + v.y * v.y + v.z * v.z + v.w * v.w;
    #pragma unroll
    for (int off = 32; off > 0; off >>= 1) s += __shfl_xor(s, off);
    if (lane == 0) { ws->sq[row] = s; Sw += s; }
  }
  cls[wave][lane * 4 + 0] = c0;
  cls[wave][lane * 4 + 1] = c1;
  cls[wave][lane * 4 + 2] = c2;
  cls[wave][lane * 4 + 3] = c3;
  if (lane == 0) swave[wave] = Sw;
  __syncthreads();
  ws->mpart[blockIdx.x][tid] = cls[0][tid] + cls[1][tid] + cls[2][tid] + cls[3][tid];
  if (tid == 0) ws->Spart[blockIdx.x] = swave[0] + swave[1] + swave[2] + swave[3];
}

// 1 block x 256 threads: reduce mpart/Spart -> bandwidth -> coef.
__global__ __launch_bounds__(256) void k_bw(Ws* __restrict__ ws) {
  __shared__ float red[4];
  int t = threadIdx.x;
  float mc = 0.f;
  for (int b = 0; b < 64; ++b) mc += ws->mpart[b][t];
  float p = mc * mc;
  #pragma unroll
  for (int off = 32; off > 0; off >>= 1) p += __shfl_xor(p, off);
  if ((t & 63) == 0) red[t >> 6] = p;
  __syncthreads();
  if (t == 0) {
    float msq = red[0] + red[1] + red[2] + red[3];
    float S = 0.f;
    for (int b = 0; b < 64; ++b) S += ws->Spart[b];
    double n = (double)NROWS;
    double sum_l2 = 2.0 * n * (double)S - 2.0 * (double)msq;
    double bw = sum_l2 / (n * n - n) / 4.0;   // / KERNEL_MUL^(KERNEL_NUM/2)
    ws->coef = (float)(1.4426950408889634 / (16.0 * bw)); // log2(e)/(16*bw)
  }
}

// Main: grid 64x64 (upper triangle active), block 256 = 4 waves, 128x128 tile.
__global__ __launch_bounds__(256) void k_main(const float* __restrict__ src,
                                              const float* __restrict__ tgt,
                                              const Ws* __restrict__ ws,
                                              double* __restrict__ out_acc) {
  int ti = blockIdx.x, tj = blockIdx.y;
  if (tj < ti) return;                        // symmetry: upper triangle only

  __shared__ __align__(16) unsigned short As[TILE][LDSTR];
  __shared__ __align__(16) unsigned short Bs[TILE][LDSTR];
  __shared__ float wsum[4];

  int tid = threadIdx.x;
  int wave = tid >> 6, lane = tid & 63;
  int wm = wave >> 1, wn = wave & 1;          // 2x2 wave grid, 64x64 each
  int lr = lane & 15, q = lane >> 4;
  int Ib = ti * TILE, Jb = tj * TILE;

  f32x4 zero = {0.f, 0.f, 0.f, 0.f};
  f32x4 acc[4][4];
  #pragma unroll
  for (int m = 0; m < 4; ++m)
    #pragma unroll
    for (int n = 0; n < 4; ++n) acc[m][n] = zero;

  int r0 = tid >> 4;    // 0..15 staging row group
  int c4 = tid & 15;    // 0..15 float4 col

  for (int kc = 0; kc < 4; ++kc) {            // K chunks of 64
    #pragma unroll
    for (int rr = 0; rr < 8; ++rr) {
      int row = rr * 16 + r0;
      const float4* ra = (const float4*)row_ptr(src, tgt, Ib + row);
      float4 va = ra[kc * 16 + c4];
      unsigned short* pa = &As[row][c4 * 4];
      pa[0] = f2bf(va.x); pa[1] = f2bf(va.y); pa[2] = f2bf(va.z); pa[3] = f2bf(va.w);
      const float4* rb = (const float4*)row_ptr(src, tgt, Jb + row);
      float4 vb = rb[kc * 16 + c4];
      unsigned short* pb = &Bs[row][c4 * 4];
      pb[0] = f2bf(vb.x); pb[1] = f2bf(vb.y); pb[2] = f2bf(vb.z); pb[3] = f2bf(vb.w);
    }
    __syncthreads();
    #pragma unroll
    for (int kk = 0; kk < 2; ++kk) {
      int koff = kk * 32 + q * 8;
      bf16x8 af[4], bfr[4];
      #pragma unroll
      for (int m = 0; m < 4; ++m)
        af[m] = *(const bf16x8*)&As[wm * 64 + m * 16 + lr][koff];
      #pragma unroll
      for (int n = 0; n < 4; ++n)
        bfr[n] = *(const bf16x8*)&Bs[wn * 64 + n * 16 + lr][koff];
      #pragma unroll
      for (int m = 0; m < 4; ++m)
        #pragma unroll
        for (int n = 0; n < 4; ++n)
          acc[m][n] = __builtin_amdgcn_mfma_f32_16x16x32_bf16(af[m], bfr[n], acc[m][n], 0, 0, 0);
    }
    __syncthreads();
  }

  // Epilogue: l2 -> 5-kernel sum via one exp2 + squarings.
  float coef = ws->coef;
  const float* sq = ws->sq;
  float lsum = 0.f;
  int ibase = Ib + wm * 64;                   // + m*16 + q*4 + r  (C/D row)
  int jbase = Jb + wn * 64;                   // + n*16 + lr       (C/D col)
  float sqj[4];
  #pragma unroll
  for (int n = 0; n < 4; ++n) sqj[n] = sq[jbase + n * 16 + lr];
  #pragma unroll
  for (int m = 0; m < 4; ++m) {
    float sqi[4];
    #pragma unroll
    for (int r = 0; r < 4; ++r) sqi[r] = sq[ibase + m * 16 + q * 4 + r];
    #pragma unroll
    for (int n = 0; n < 4; ++n) {
      f32x4 g = acc[m][n];
      #pragma unroll
      for (int r = 0; r < 4; ++r) {
        float l2 = fmaxf(sqi[r] + sqj[n] - 2.f * g[r], 0.f);
        float t  = exp2f(-l2 * coef);         // exp(-l2/(16*bw))
        float t2 = t * t, t4 = t2 * t2, t8 = t4 * t4, t16 = t8 * t8;
        lsum += ((t + t2) + (t4 + t8)) + t16;
      }
    }
  }
  #pragma unroll
  for (int off = 32; off > 0; off >>= 1) lsum += __shfl_xor(lsum, off);
  if (lane == 0) wsum[wave] = lsum;
  __syncthreads();
  if (tid == 0) {
    float tot = wsum[0] + wsum[1] + wsum[2] + wsum[3];
    float sA = (ti < 32) ? 1.f : -1.f;        // tile row-block sign (B=4096 = 32 tiles)
    float sB = (tj < 32) ? 1.f : -1.f;
    float fac = sA * sB * ((ti == tj) ? 1.f : 2.f);
    atomicAdd(out_acc, (double)(fac * tot));
  }
}

__global__ void k_final(const Ws* __restrict__ ws, float* __restrict__ out) {
  if (threadIdx.x == 0)
    out[0] = (float)(ws->signed_sum / ((double)BHALF * (double)BHALF));
}

extern "C" void kernel_launch(void* const* d_in, const int* in_sizes, int n_in,
                              void* d_out, int out_size, void* d_ws, size_t ws_size,
                              hipStream_t stream) {
  const float* src = (const float*)d_in[0];
  const float* tgt = (const float*)d_in[1];
  Ws* ws = (Ws*)d_ws;
  float* out = (float*)d_out;

  hipLaunchKernelGGL(k_init,     dim3(1),      dim3(64),  0, stream, ws);
  hipLaunchKernelGGL(k_rowstats, dim3(64),     dim3(256), 0, stream, src, tgt, ws);
  hipLaunchKernelGGL(k_bw,       dim3(1),      dim3(256), 0, stream, ws);
  hipLaunchKernelGGL(k_main,     dim3(64, 64), dim3(256), 0, stream, src, tgt, ws,
                     &ws->signed_sum);
  hipLaunchKernelGGL(k_final,    dim3(1),      dim3(1),   0, stream, ws, out);
}

// Round 2
// 158.417 us; speedup vs baseline: 1.3133x; 1.3133x over previous
//
#include <hip/hip_runtime.h>

// MMD loss: source (4096,256) fp32, target (4096,256) fp32 -> scalar fp32.
// bandwidth via closed form: sum(l2) = 2n*S - 2*||m||^2 (relu effect negligible).
// Prep: fp32 -> bf16 matrix (once), row norms sq[], column sums -> coef
//       (last-block fused reduction).
// Main: m97-style 128x128 tile GEMM (16x16x32 bf16 MFMA, global_load_lds
//       width=16, unpadded 128x64 LDS tiles), epilogue K = t+t^2+t^4+t^8+t^16
//       with t = exp2(-l2*coef); triangular block packing; last block writes out.

#define NROWS 8192
#define BHALF 4096
#define DDIM  256
#define TILE  128
#define NTILE 64
#define NBLK  2080   // NTILE*(NTILE+1)/2

typedef __attribute__((ext_vector_type(8))) short bf16x8;
typedef __attribute__((ext_vector_type(4))) float f32x4;
typedef __attribute__((ext_vector_type(4))) unsigned short u16x4;

struct Ws {
  double signed_sum;        // zeroed by memset
  unsigned int ctr1;        // zeroed by memset
  unsigned int ctr2;        // zeroed by memset
  float  coef;
  float  pad0;
  float  Spart[64];
  float  mpart[64][256];
  float  sq[NROWS];
};

__device__ __forceinline__ unsigned short f2bf(float x) {
  unsigned int u = __builtin_bit_cast(unsigned int, x);
  return (unsigned short)((u + 0x7fffu + ((u >> 16) & 1u)) >> 16);
}

__device__ __forceinline__ const float* row_ptr(const float* src, const float* tgt, int i) {
  return (i < BHALF) ? (src + (size_t)i * DDIM) : (tgt + (size_t)(i - BHALF) * DDIM);
}

// 64 blocks x 256 threads. Converts to bf16 (if tb), computes sq[], column
// sums; LAST block (fence+counter) reduces to bandwidth -> ws->coef.
__global__ __launch_bounds__(256) void k_prep(const float* __restrict__ src,
                                              const float* __restrict__ tgt,
                                              Ws* __restrict__ ws,
                                              unsigned short* __restrict__ tb,
                                              int conv) {
  __shared__ float cls[4][256];
  __shared__ float swave[4];
  __shared__ int isLast;
  int tid = threadIdx.x, wave = tid >> 6, lane = tid & 63;
  int wave_g = blockIdx.x * 4 + wave;          // 0..255, 32 rows each
  float c0 = 0.f, c1 = 0.f, c2 = 0.f, c3 = 0.f, Sw = 0.f;
  for (int r = 0; r < 32; ++r) {
    int row = wave_g * 32 + r;
    const float4* rp = (const float4*)row_ptr(src, tgt, row);
    float4 v = rp[lane];
    if (conv) {
      u16x4 b = { f2bf(v.x), f2bf(v.y), f2bf(v.z), f2bf(v.w) };
      *(u16x4*)&tb[(size_t)row * DDIM + lane * 4] = b;
    }
    c0 += v.x; c1 += v.y; c2 += v.z; c3 += v.w;
    float s = v.x * v.x + v.y * v.y + v.z * v.z + v.w * v.w;
    #pragma unroll
    for (int off = 32; off > 0; off >>= 1) s += __shfl_xor(s, off);
    if (lane == 0) { ws->sq[row] = s; Sw += s; }
  }
  cls[wave][lane * 4 + 0] = c0;
  cls[wave][lane * 4 + 1] = c1;
  cls[wave][lane * 4 + 2] = c2;
  cls[wave][lane * 4 + 3] = c3;
  if (lane == 0) swave[wave] = Sw;
  __syncthreads();
  ws->mpart[blockIdx.x][tid] = cls[0][tid] + cls[1][tid] + cls[2][tid] + cls[3][tid];
  if (tid == 0) ws->Spart[blockIdx.x] = swave[0] + swave[1] + swave[2] + swave[3];

  // last-block bandwidth reduction
  __threadfence();
  __syncthreads();
  if (tid == 0) {
    unsigned int old = atomicAdd(&ws->ctr1, 1u);
    isLast = (old == 63u);
  }
  __syncthreads();
  if (!isLast) return;

  __shared__ float red[4];
  float mc = 0.f;
  for (int b = 0; b < 64; ++b) mc += ws->mpart[b][tid];
  float p = mc * mc;
  #pragma unroll
  for (int off = 32; off > 0; off >>= 1) p += __shfl_xor(p, off);
  if ((tid & 63) == 0) red[tid >> 6] = p;
  __syncthreads();
  if (tid == 0) {
    float msq = red[0] + red[1] + red[2] + red[3];
    float S = 0.f;
    for (int b = 0; b < 64; ++b) S += ws->Spart[b];
    double n = (double)NROWS;
    double sum_l2 = 2.0 * n * (double)S - 2.0 * (double)msq;
    double bw = sum_l2 / (n * n - n) / 4.0;   // / KERNEL_MUL^(KERNEL_NUM/2)
    ws->coef = (float)(1.4426950408889634 / (16.0 * bw)); // log2(e)/(16*bw)
  }
}

// Main: NBLK blocks (upper triangle, packed), 256 thr = 4 waves, 128x128 tile.
template <int FAST>
__global__ __launch_bounds__(256) void k_main(const unsigned short* __restrict__ tb,
                                              const float* __restrict__ src,
                                              const float* __restrict__ tgt,
                                              Ws* __restrict__ ws,
                                              float* __restrict__ out) {
  // triangular decode: idx -> (ti, tj), ti<=tj
  int idx = blockIdx.x;
  int ti = (int)((129.0 - sqrt(129.0 * 129.0 - 8.0 * (double)idx)) * 0.5);
  while (64 * (ti + 1) - ((ti + 1) * ti) / 2 <= idx) ++ti;
  while (64 * ti - (ti * (ti - 1)) / 2 > idx) --ti;
  int tj = ti + (idx - (64 * ti - (ti * (ti - 1)) / 2));

  __shared__ __align__(16) unsigned short As[TILE * 64];
  __shared__ __align__(16) unsigned short Bs[TILE * 64];
  __shared__ float wsum[4];
  __shared__ int isLast;

  int tid = threadIdx.x;
  int wave = tid >> 6, lane = tid & 63;
  int wm = wave >> 1, wn = wave & 1;          // 2x2 wave grid, 64x64 each
  int lr = lane & 15, q = lane >> 4;
  int Ib = ti * TILE, Jb = tj * TILE;

  f32x4 zero = {0.f, 0.f, 0.f, 0.f};
  f32x4 acc[4][4];
  #pragma unroll
  for (int m = 0; m < 4; ++m)
    #pragma unroll
    for (int n = 0; n < 4; ++n) acc[m][n] = zero;

  // FAST staging addresses: lane -> (row = lane/8, 16B chunk = lane%8)
  const unsigned short* ga = nullptr; const unsigned short* gb = nullptr;
  if (FAST) {
    ga = tb + (size_t)(Ib + wave * 32 + (lane >> 3)) * DDIM + (lane & 7) * 8;
    gb = tb + (size_t)(Jb + wave * 32 + (lane >> 3)) * DDIM + (lane & 7) * 8;
  }
  int r0 = tid >> 4, c4 = tid & 15;           // slow-path staging coords

  for (int kc = 0; kc < 4; ++kc) {            // K chunks of 64
    if (FAST) {
      #pragma unroll
      for (int t = 0; t < 4; ++t) {
        __builtin_amdgcn_global_load_lds(
            (const __attribute__((address_space(1))) void*)(ga + (size_t)t * 8 * DDIM + kc * 64),
            (__attribute__((address_space(3))) void*)(&As[(wave * 32 + t * 8) * 64]),
            16, 0, 0);
        __builtin_amdgcn_global_load_lds(
            (const __attribute__((address_space(1))) void*)(gb + (size_t)t * 8 * DDIM + kc * 64),
            (__attribute__((address_space(3))) void*)(&Bs[(wave * 32 + t * 8) * 64]),
            16, 0, 0);
      }
    } else {
      #pragma unroll
      for (int rr = 0; rr < 8; ++rr) {
        int row = rr * 16 + r0;
        const float4* ra = (const float4*)row_ptr(src, tgt, Ib + row);
        float4 va = ra[kc * 16 + c4];
        unsigned short* pa = &As[row * 64 + c4 * 4];
        pa[0] = f2bf(va.x); pa[1] = f2bf(va.y); pa[2] = f2bf(va.z); pa[3] = f2bf(va.w);
        const float4* rb = (const float4*)row_ptr(src, tgt, Jb + row);
        float4 vb = rb[kc * 16 + c4];
        unsigned short* pb = &Bs[row * 64 + c4 * 4];
        pb[0] = f2bf(vb.x); pb[1] = f2bf(vb.y); pb[2] = f2bf(vb.z); pb[3] = f2bf(vb.w);
      }
    }
    __syncthreads();
    #pragma unroll
    for (int kk = 0; kk < 2; ++kk) {
      int koff = kk * 32 + q * 8;
      bf16x8 af[4], bfr[4];
      #pragma unroll
      for (int m = 0; m < 4; ++m)
        af[m] = *(const bf16x8*)&As[(wm * 64 + m * 16 + lr) * 64 + koff];
      #pragma unroll
      for (int n = 0; n < 4; ++n)
        bfr[n] = *(const bf16x8*)&Bs[(wn * 64 + n * 16 + lr) * 64 + koff];
      #pragma unroll
      for (int m = 0; m < 4; ++m)
        #pragma unroll
        for (int n = 0; n < 4; ++n)
          acc[m][n] = __builtin_amdgcn_mfma_f32_16x16x32_bf16(af[m], bfr[n], acc[m][n], 0, 0, 0);
    }
    __syncthreads();
  }

  // Epilogue: l2 -> 5-kernel sum via one exp2 + squarings.
  float coef = ws->coef;
  const float* sq = ws->sq;
  float lsum = 0.f;
  int ibase = Ib + wm * 64;                   // + m*16 + q*4 + r  (C/D row)
  int jbase = Jb + wn * 64;                   // + n*16 + lr       (C/D col)
  float sqj[4];
  #pragma unroll
  for (int n = 0; n < 4; ++n) sqj[n] = sq[jbase + n * 16 + lr];
  #pragma unroll
  for (int m = 0; m < 4; ++m) {
    float sqi[4];
    #pragma unroll
    for (int r = 0; r < 4; ++r) sqi[r] = sq[ibase + m * 16 + q * 4 + r];
    #pragma unroll
    for (int n = 0; n < 4; ++n) {
      f32x4 g = acc[m][n];
      #pragma unroll
      for (int r = 0; r < 4; ++r) {
        float l2 = fmaxf(sqi[r] + sqj[n] - 2.f * g[r], 0.f);
        float t  = exp2f(-l2 * coef);         // exp(-l2/(16*bw))
        float t2 = t * t, t4 = t2 * t2, t8 = t4 * t4, t16 = t8 * t8;
        lsum += ((t + t2) + (t4 + t8)) + t16;
      }
    }
  }
  #pragma unroll
  for (int off = 32; off > 0; off >>= 1) lsum += __shfl_xor(lsum, off);
  if (lane == 0) wsum[wave] = lsum;
  __syncthreads();
  if (tid == 0) {
    float tot = wsum[0] + wsum[1] + wsum[2] + wsum[3];
    float sA = (ti < 32) ? 1.f : -1.f;        // B=4096 = 32 tiles of 128
    float sB = (tj < 32) ? 1.f : -1.f;
    float fac = sA * sB * ((ti == tj) ? 1.f : 2.f);
    atomicAdd(&ws->signed_sum, (double)(fac * tot));
    __threadfence();
    unsigned int old = atomicAdd(&ws->ctr2, 1u);
    if (old == (unsigned)(NBLK - 1)) {
      __threadfence();
      double tot_all = atomicAdd(&ws->signed_sum, 0.0);  // atomic read
      out[0] = (float)(tot_all / ((double)BHALF * (double)BHALF));
    }
  }
}

extern "C" void kernel_launch(void* const* d_in, const int* in_sizes, int n_in,
                              void* d_out, int out_size, void* d_ws, size_t ws_size,
                              hipStream_t stream) {
  const float* src = (const float*)d_in[0];
  const float* tgt = (const float*)d_in[1];
  Ws* ws = (Ws*)d_ws;
  float* out = (float*)d_out;

  size_t wsoff = (sizeof(Ws) + 255) & ~(size_t)255;
  size_t need = wsoff + (size_t)NROWS * DDIM * 2;
  bool fast = ws_size >= need;
  unsigned short* tb = fast ? (unsigned short*)((char*)d_ws + wsoff) : nullptr;

  hipMemsetAsync(d_ws, 0, 16, stream);   // signed_sum + ctr1 + ctr2
  hipLaunchKernelGGL(k_prep, dim3(64), dim3(256), 0, stream, src, tgt, ws, tb,
                     fast ? 1 : 0);
  if (fast)
    hipLaunchKernelGGL((k_main<1>), dim3(NBLK), dim3(256), 0, stream, tb, src, tgt, ws, out);
  else
    hipLaunchKernelGGL((k_main<0>), dim3(NBLK), dim3(256), 0, stream, tb, src, tgt, ws, out);
}